// Round 1
// baseline (107.223 us; speedup 1.0000x reference)
//
#include <hip/hip_runtime.h>

// Reference returns (x, y) unchanged — _block_scores is computed and discarded.
// d_out = concat(flat(x), flat(y)) in float32. Pure D2D copy, memory-bound.
// 256 MiB read + 256 MiB write -> ~85 us at 6.3 TB/s achievable HBM BW.

extern "C" void kernel_launch(void* const* d_in, const int* in_sizes, int n_in,
                              void* d_out, int out_size, void* d_ws, size_t ws_size,
                              hipStream_t stream) {
    const size_t nx = (size_t)in_sizes[0];  // x: B*Cx*H*W = 33554432 f32
    const size_t ny = (size_t)in_sizes[1];  // y: B*Cy*H*W = 33554432 f32

    hipMemcpyAsync(d_out, d_in[0], nx * sizeof(float),
                   hipMemcpyDeviceToDevice, stream);
    hipMemcpyAsync((char*)d_out + nx * sizeof(float), d_in[1], ny * sizeof(float),
                   hipMemcpyDeviceToDevice, stream);
}